// Round 5
// baseline (73.203 us; speedup 1.0000x reference)
//
#include <hip/hip_runtime.h>

#define DIM 4096

constexpr float LOG2E = 1.44269504088896340736f;
constexpr float TWO_LOG2E = 2.0f * LOG2E;

// ---------- 2-channel pack: every op is two independent dataflow chains ----------
struct F2 { float a, b; };

__device__ __forceinline__ float fexp2s(float x) { return __builtin_amdgcn_exp2f(x); }
__device__ __forceinline__ float frcps(float x) { return __builtin_amdgcn_rcpf(x); }

__device__ __forceinline__ F2 ld2(const float* p) {
  float2 v = *(const float2*)p;
  return {v.x, v.y};
}
__device__ __forceinline__ F2 fadd(F2 u, F2 v) { return {u.a + v.a, u.b + v.b}; }
__device__ __forceinline__ F2 fmul(F2 u, F2 v) { return {u.a * v.a, u.b * v.b}; }
__device__ __forceinline__ F2 ffma2(F2 x, F2 y, F2 z) {
  return {fmaf(x.a, y.a, z.a), fmaf(x.b, y.b, z.b)};
}
__device__ __forceinline__ F2 addc(F2 u, float c) { return {u.a + c, u.b + c}; }
__device__ __forceinline__ F2 rsubc(float c, F2 u) { return {c - u.a, c - u.b}; }
__device__ __forceinline__ F2 mulc(F2 u, float c) { return {u.a * c, u.b * c}; }
// e = 2^min(-u, 30): clamped exponential. sigma-error <= 2^-30; keeps all fused
// denominator products finite (<= 2^120 < FLT_MAX).
__device__ __forceinline__ F2 eclamp(F2 u) {
  return {fexp2s(fminf(-u.a, 30.0f)), fexp2s(fminf(-u.b, 30.0f))};
}
__device__ __forceinline__ F2 fexp2v(F2 u) { return {fexp2s(u.a), fexp2s(u.b)}; }
__device__ __forceinline__ F2 frcpv(F2 u) { return {frcps(u.a), frcps(u.b)}; }

struct P2 {
  F2 wf, uf, bf;   // pre-scaled by log2e
  F2 wi, ui, bi;   // pre-scaled by log2e
  F2 wc, uc, bc;   // pre-scaled by 2*log2e
  F2 wo, uo, bo;   // pre-scaled by log2e
};

__device__ __forceinline__ F2 ldscale(const float* p, int d2, float s) {
  float2 v = *(const float2*)(p + d2);
  return {v.x * s, v.y * s};
}

__device__ __forceinline__ P2 load_params(
    int d2,
    const float* wf, const float* uf, const float* bf,
    const float* wi, const float* ui, const float* bi,
    const float* wc, const float* uc, const float* bc,
    const float* wo, const float* uo, const float* bo) {
  P2 p;
  p.wf = ldscale(wf, d2, LOG2E);     p.uf = ldscale(uf, d2, LOG2E);     p.bf = ldscale(bf, d2, LOG2E);
  p.wi = ldscale(wi, d2, LOG2E);     p.ui = ldscale(ui, d2, LOG2E);     p.bi = ldscale(bi, d2, LOG2E);
  p.wc = ldscale(wc, d2, TWO_LOG2E); p.uc = ldscale(uc, d2, TWO_LOG2E); p.bc = ldscale(bc, d2, TWO_LOG2E);
  p.wo = ldscale(wo, d2, LOG2E);     p.uo = ldscale(uo, d2, LOG2E);     p.bo = ldscale(bo, d2, LOG2E);
  return p;
}

// Leaf (h_sum = 0): ct = [ (1-eg)(1+ef) + (1+ei)(1+eg) ] / [ (1+ef)(1+ei)(1+eg) ]
// then h = sigma(ao)*tanh(ct) = (1-ec)/((1+eo)(1+ec)).  5 exp2 + 2 rcp, exact.
__device__ __forceinline__ F2 leaf_node(F2 x, const P2& p) {
  F2 ef = eclamp(ffma2(p.wf, x, p.bf));
  F2 ei = eclamp(ffma2(p.wi, x, p.bi));
  F2 eg = eclamp(ffma2(p.wc, x, p.bc));
  F2 sf = addc(ef, 1.0f);
  F2 si = addc(ei, 1.0f);
  F2 t1 = ffma2(si, eg, si);                    // (1+ei)(1+eg)
  F2 num = ffma2(rsubc(1.0f, eg), sf, t1);
  F2 ct = fmul(num, frcpv(fmul(t1, sf)));
  F2 eo = eclamp(ffma2(p.wo, x, p.bo));
  F2 ec = fexp2v(mulc(ct, -TWO_LOG2E));         // e^{-2ct}, |ct|<=2 here
  F2 so = addc(eo, 1.0f);
  return fmul(rsubc(1.0f, ec), frcpv(ffma2(so, ec, so)));
}

// Inner node, fused single-rcp ct:
//   fsum = (2+e1+e2)/((1+e1)(1+e2)),  itgt = (1-eg)/((1+ei)(1+eg))
//   ct   = (fN*iD + iN*fD) / (fD*iD)          <- one rcp
//   h    = (1-ec)/((1+eo)(1+ec))
// 6 exp2 + 2 rcp, exact up to the 2^-30 clamps.
__device__ __forceinline__ F2 inner_node(F2 x, F2 hl, F2 hr, const P2& p, F2& ct_out) {
  F2 hs = fadd(hl, hr);
  F2 af = ffma2(p.wf, x, p.bf);
  F2 e1 = eclamp(ffma2(p.uf, hl, af));
  F2 e2 = eclamp(ffma2(p.uf, hr, af));
  F2 s1 = addc(e1, 1.0f);
  F2 fD = ffma2(s1, e2, s1);                    // (1+e1)(1+e2)
  F2 fN = addc(fadd(e1, e2), 2.0f);             // 2+e1+e2
  F2 ei = eclamp(ffma2(p.ui, hs, ffma2(p.wi, x, p.bi)));
  F2 eg = eclamp(ffma2(p.uc, hs, ffma2(p.wc, x, p.bc)));
  F2 si = addc(ei, 1.0f);
  F2 iD = ffma2(si, eg, si);                    // (1+ei)(1+eg)
  F2 iN = rsubc(1.0f, eg);
  F2 num = ffma2(iN, fD, fmul(fN, iD));
  F2 ct = fmul(num, frcpv(fmul(fD, iD)));
  ct_out = ct;
  F2 eo = eclamp(ffma2(p.uo, hs, ffma2(p.wo, x, p.bo)));
  F2 ec = fexp2v(mulc(ct, -TWO_LOG2E));         // |ct| <= 3, no clamp needed
  F2 so = addc(eo, 1.0f);
  return fmul(rsubc(1.0f, ec), frcpv(ffma2(so, ec, so)));
}

// Breadth-first depth-3 tile rooted at level-9 node r: 8 leaves -> 4 -> 2 -> 1.
// All 15 row loads issued up front; 8 independent leaf chains give the
// scheduler in-wave ILP to hide trans/memory latency.
__device__ __forceinline__ F2 sub8(const float* __restrict__ tvd, int r, const P2& p) {
  const float* lp = tvd + (size_t)(8 * r + 7) * DIM;      // leaves 8r+7..8r+14
  F2 x0 = ld2(lp);
  F2 x1 = ld2(lp + DIM);
  F2 x2 = ld2(lp + 2 * DIM);
  F2 x3 = ld2(lp + 3 * DIM);
  F2 x4 = ld2(lp + 4 * DIM);
  F2 x5 = ld2(lp + 5 * DIM);
  F2 x6 = ld2(lp + 6 * DIM);
  F2 x7 = ld2(lp + 7 * DIM);
  const float* mp = tvd + (size_t)(4 * r + 3) * DIM;      // level 11: 4r+3..4r+6
  F2 xm0 = ld2(mp);
  F2 xm1 = ld2(mp + DIM);
  F2 xm2 = ld2(mp + 2 * DIM);
  F2 xm3 = ld2(mp + 3 * DIM);
  const float* np = tvd + (size_t)(2 * r + 1) * DIM;      // level 10: 2r+1, 2r+2
  F2 xn0 = ld2(np);
  F2 xn1 = ld2(np + DIM);
  F2 xr = ld2(tvd + (size_t)r * DIM);                     // level 9: r

  F2 L0 = leaf_node(x0, p);
  F2 L1 = leaf_node(x1, p);
  F2 L2 = leaf_node(x2, p);
  F2 L3 = leaf_node(x3, p);
  F2 L4 = leaf_node(x4, p);
  F2 L5 = leaf_node(x5, p);
  F2 L6 = leaf_node(x6, p);
  F2 L7 = leaf_node(x7, p);
  F2 dct;
  F2 M0 = inner_node(xm0, L0, L1, p, dct);
  F2 M1 = inner_node(xm1, L2, L3, p, dct);
  F2 M2 = inner_node(xm2, L4, L5, p, dct);
  F2 M3 = inner_node(xm3, L6, L7, p, dct);
  F2 N0 = inner_node(xn0, M0, M1, p, dct);
  F2 N1 = inner_node(xn1, M2, M3, p, dct);
  return inner_node(xr, N0, N1, p, dct);
}

// Phase 1: 128 subtrees (roots at level 7) x 8 channel-blocks (512 ch each).
// Each thread: 2 channels, levels 12..7 (127 nodes), writes h7 to ws.
__global__ __launch_bounds__(256) void treelstm_p1(
    const float* __restrict__ tv,
    const float* __restrict__ wf, const float* __restrict__ uf, const float* __restrict__ bf,
    const float* __restrict__ wi, const float* __restrict__ ui, const float* __restrict__ bi,
    const float* __restrict__ wc, const float* __restrict__ uc, const float* __restrict__ bc,
    const float* __restrict__ wo, const float* __restrict__ uo, const float* __restrict__ bo,
    float* __restrict__ ws) {
  const int cb = blockIdx.x & 7;                 // channel block (512 channels)
  const int g  = blockIdx.x >> 3;                // subtree 0..127
  const int d2 = cb * 512 + threadIdx.x * 2;     // first of 2 channels
  const float* tvd = tv + d2;

  const P2 p = load_params(d2, wf, uf, bf, wi, ui, bi, wc, uc, bc, wo, uo, bo);

  // level-9 descendants of root 127+g: 511+4g .. 514+4g
  F2 h9_0 = sub8(tvd, 511 + 4 * g, p);
  F2 h9_1 = sub8(tvd, 512 + 4 * g, p);
  F2 h9_2 = sub8(tvd, 513 + 4 * g, p);
  F2 h9_3 = sub8(tvd, 514 + 4 * g, p);

  F2 dct;
  F2 x8a = ld2(tvd + (size_t)(255 + 2 * g) * DIM);
  F2 x8b = ld2(tvd + (size_t)(256 + 2 * g) * DIM);
  F2 h8a = inner_node(x8a, h9_0, h9_1, p, dct);
  F2 h8b = inner_node(x8b, h9_2, h9_3, p, dct);
  F2 x7 = ld2(tvd + (size_t)(127 + g) * DIM);
  F2 h7 = inner_node(x7, h8a, h8b, p, dct);

  float2 st = {h7.a, h7.b};
  *(float2*)&ws[(size_t)g * DIM + d2] = st;
}

// Phase 2: levels 6..0 from staged h7. 8 blocks x 256 threads, 2 ch/thread.
template <int LVL>
__device__ __forceinline__ F2 top_h(const float* __restrict__ tvd,
                                    const float* __restrict__ wsd, int node,
                                    const P2& p, F2& ct_out) {
  if constexpr (LVL == 7) {
    ct_out = {0.0f, 0.0f};
    return ld2(wsd + (size_t)(node - 127) * DIM);
  } else {
    F2 cl, cr;
    F2 hl = top_h<LVL + 1>(tvd, wsd, 2 * node + 1, p, cl);
    F2 hr = top_h<LVL + 1>(tvd, wsd, 2 * node + 2, p, cr);
    F2 x = ld2(tvd + (size_t)node * DIM);
    return inner_node(x, hl, hr, p, ct_out);
  }
}

__global__ __launch_bounds__(256) void treelstm_p2(
    const float* __restrict__ tv,
    const float* __restrict__ wf, const float* __restrict__ uf, const float* __restrict__ bf,
    const float* __restrict__ wi, const float* __restrict__ ui, const float* __restrict__ bi,
    const float* __restrict__ wc, const float* __restrict__ uc, const float* __restrict__ bc,
    const float* __restrict__ wo, const float* __restrict__ uo, const float* __restrict__ bo,
    const float* __restrict__ ws, float* __restrict__ out) {
  const int d2 = blockIdx.x * 512 + threadIdx.x * 2;

  const P2 p = load_params(d2, wf, uf, bf, wi, ui, bi, wc, uc, bc, wo, uo, bo);

  F2 ct;
  F2 h = top_h<0>(tv + d2, ws + d2, 0, p, ct);
  float2 sh = {h.a, h.b};
  float2 sc = {ct.a, ct.b};
  *(float2*)&out[d2] = sh;
  *(float2*)&out[DIM + d2] = sc;
}

extern "C" void kernel_launch(void* const* d_in, const int* in_sizes, int n_in,
                              void* d_out, int out_size, void* d_ws, size_t ws_size,
                              hipStream_t stream) {
  const float* tv = (const float*)d_in[0];
  // d_in[1] = depth (int, 13) -- structure hard-coded to depth 13.
  const float* wf = (const float*)d_in[2];
  const float* uf = (const float*)d_in[3];
  const float* bf = (const float*)d_in[4];
  const float* wi = (const float*)d_in[5];
  const float* ui = (const float*)d_in[6];
  const float* bi = (const float*)d_in[7];
  const float* wc = (const float*)d_in[8];
  const float* uc = (const float*)d_in[9];
  const float* bc = (const float*)d_in[10];
  const float* wo = (const float*)d_in[11];
  const float* uo = (const float*)d_in[12];
  const float* bo = (const float*)d_in[13];

  float* ws = (float*)d_ws;   // needs 128 * 4096 * 4 B = 2 MiB (verified available rounds 2-4)
  float* out = (float*)d_out; // 8192 floats: h then c

  treelstm_p1<<<dim3(128 * 8), dim3(256), 0, stream>>>(
      tv, wf, uf, bf, wi, ui, bi, wc, uc, bc, wo, uo, bo, ws);

  treelstm_p2<<<dim3(8), dim3(256), 0, stream>>>(
      tv, wf, uf, bf, wi, ui, bi, wc, uc, bc, wo, uo, bo, ws, out);
}

// Round 6
// 57.685 us; speedup vs baseline: 1.2690x; 1.2690x over previous
//
#include <hip/hip_runtime.h>

#define DIM 4096
#define LEAF_LVL 12      // leaves: nodes [4095, 8190]

constexpr float LOG2E = 1.44269504088896340736f;
constexpr float TWO_LOG2E = 2.0f * LOG2E;

struct Params {
  float wf, uf, bf;   // pre-scaled by log2e
  float wi, ui, bi;   // pre-scaled by log2e
  float wc, uc, bc;   // pre-scaled by 2*log2e  (tanh uses e^{-2z} = 2^{-2z*log2e})
  float wo, uo, bo;   // pre-scaled by log2e
};

__device__ __forceinline__ float frcp(float x) { return __builtin_amdgcn_rcpf(x); }
__device__ __forceinline__ float fexp2(float x) { return __builtin_amdgcn_exp2f(x); }

// sigma(z1)+sigma(z2), args pre-scaled by log2e. Exact identity:
//   (2+e1+e2) / ((1+e1)(1+e2)),  e=2^-u.  2 exp2 + 1 rcp.
__device__ __forceinline__ float sig_sum2(float u1, float u2) {
  float e1 = fexp2(-u1);
  float e2 = fexp2(-u2);
  float s1 = 1.0f + e1;
  float den = fmaf(s1, e2, s1);        // (1+e1)(1+e2)
  float num = (2.0f + e1) + e2;
  return num * frcp(den);
}

// sigma(zi)*tanh(zg): ui = zi*log2e, ug = 2*zg*log2e. Exact identity:
//   (1-eg) / ((1+ei)(1+eg)).  2 exp2 + 1 rcp.
// eg clamped to 2^60 so num stays finite; den<=2^114 finite; rcp(inf)=0 paths
// all land within 2^-21 of the true value.
__device__ __forceinline__ float sig_mul_tanh(float ui, float ug) {
  float ei = fexp2(-ui);
  float eg = fexp2(fminf(-ug, 60.0f));
  float si = 1.0f + ei;
  float den = fmaf(si, eg, si);        // (1+ei)(1+eg)
  float num = 1.0f - eg;
  return num * frcp(den);
}

__device__ __forceinline__ float leaf_node(float x, const Params& p) {
  // h_sum = 0: ct = sigma(af) + sigma(ai)*tanh(ag) over one shared denominator:
  //   ct = [ (1-eg)(1+ef) + (1+ei)(1+eg) ] / [ (1+ef)(1+ei)(1+eg) ]   3 exp2 + 1 rcp
  float af = fmaf(p.wf, x, p.bf);
  float ai = fmaf(p.wi, x, p.bi);
  float ag = fmaf(p.wc, x, p.bc);
  float ef = fexp2(-af);
  float ei = fexp2(-ai);
  float eg = fexp2(fminf(-ag, 60.0f));
  float sf = 1.0f + ef;
  float si = 1.0f + ei;
  float t1 = fmaf(si, eg, si);                 // (1+ei)(1+eg)
  float den = t1 * sf;
  float num = fmaf(1.0f - eg, sf, t1);
  float ct = num * frcp(den);
  return sig_mul_tanh(fmaf(p.wo, x, p.bo), ct * TWO_LOG2E);
}

__device__ __forceinline__ float inner_node(float x, float hl, float hr,
                                            const Params& p, float& ct_out) {
  float hs = hl + hr;
  float af = fmaf(p.wf, x, p.bf);
  float fsum = sig_sum2(fmaf(p.uf, hl, af), fmaf(p.uf, hr, af));
  float itgt = sig_mul_tanh(fmaf(p.ui, hs, fmaf(p.wi, x, p.bi)),
                            fmaf(p.uc, hs, fmaf(p.wc, x, p.bc)));
  float ct = itgt + fsum;
  ct_out = ct;
  // |ct| <= 3 so the tanh arg never needs clamping.
  return sig_mul_tanh(fmaf(p.uo, hs, fmaf(p.wo, x, p.bo)), ct * TWO_LOG2E);
}

// Compile-time-unrolled DFS; all state in registers (no runtime-indexed arrays).
template <int LVL>
__device__ __forceinline__ float subtree_h(const float* __restrict__ tv, int node,
                                           int d, const Params& p) {
  if constexpr (LVL == LEAF_LVL) {
    float x = tv[(size_t)node * DIM + d];
    return leaf_node(x, p);
  } else {
    float hl = subtree_h<LVL + 1>(tv, 2 * node + 1, d, p);
    float hr = subtree_h<LVL + 1>(tv, 2 * node + 2, d, p);
    float x = tv[(size_t)node * DIM + d];
    float ct;
    return inner_node(x, hl, hr, p, ct);
  }
}

__device__ __forceinline__ Params load_params(
    int d,
    const float* wf, const float* uf, const float* bf,
    const float* wi, const float* ui, const float* bi,
    const float* wc, const float* uc, const float* bc,
    const float* wo, const float* uo, const float* bo) {
  Params p;
  p.wf = wf[d] * LOG2E;     p.uf = uf[d] * LOG2E;     p.bf = bf[d] * LOG2E;
  p.wi = wi[d] * LOG2E;     p.ui = ui[d] * LOG2E;     p.bi = bi[d] * LOG2E;
  p.wc = wc[d] * TWO_LOG2E; p.uc = uc[d] * TWO_LOG2E; p.bc = bc[d] * TWO_LOG2E;
  p.wo = wo[d] * LOG2E;     p.uo = uo[d] * LOG2E;     p.bo = bo[d] * LOG2E;
  return p;
}

// Phase 1: (2^SPLIT subtrees) x (16 channel-blocks) blocks of 256 threads.
// Reduces levels 12..SPLIT in registers; writes h(level-SPLIT node) to ws.
// __launch_bounds__(256, 6): cap VGPR at ~85 (6 waves/SIMD) -- gives the
// scheduler ~2.5x the registers of the default 8-wave target, to interleave
// independent sibling chains and hoist tile loads (stall-hiding experiment).
template <int SPLIT>
__global__ __launch_bounds__(256, 6) void treelstm_p1(
    const float* __restrict__ tv,
    const float* __restrict__ wf, const float* __restrict__ uf, const float* __restrict__ bf,
    const float* __restrict__ wi, const float* __restrict__ ui, const float* __restrict__ bi,
    const float* __restrict__ wc, const float* __restrict__ uc, const float* __restrict__ bc,
    const float* __restrict__ wo, const float* __restrict__ uo, const float* __restrict__ bo,
    float* __restrict__ ws) {
  const int cb = blockIdx.x & 15;          // channel block
  const int g  = blockIdx.x >> 4;          // subtree index
  const int d  = cb * 256 + threadIdx.x;   // channel

  const Params p = load_params(d, wf, uf, bf, wi, ui, bi, wc, uc, bc, wo, uo, bo);

  const int root = ((1 << SPLIT) - 1) + g; // level-SPLIT node
  float h = subtree_h<SPLIT>(tv, root, d, p);
  ws[(size_t)g * DIM + d] = h;
}

// Top-of-tree DFS: leaves of this phase are the staged level-SPLIT h values.
template <int SPLIT, int LVL>
__device__ __forceinline__ float top_h(const float* __restrict__ tv,
                                       const float* __restrict__ ws, int node, int d,
                                       const Params& p, float& ct_out) {
  if constexpr (LVL == SPLIT) {
    ct_out = 0.0f;  // never consumed at this level
    return ws[(size_t)(node - ((1 << SPLIT) - 1)) * DIM + d];
  } else {
    float ct_l, ct_r;
    float hl = top_h<SPLIT, LVL + 1>(tv, ws, 2 * node + 1, d, p, ct_l);
    float hr = top_h<SPLIT, LVL + 1>(tv, ws, 2 * node + 2, d, p, ct_r);
    float x = tv[(size_t)node * DIM + d];
    return inner_node(x, hl, hr, p, ct_out);
  }
}

// Phase 2: 16 blocks x 256 threads = 4096 threads (one per channel).
// Reduces levels SPLIT-1..0; writes root h to out[0..DIM), root c to out[DIM..2*DIM).
template <int SPLIT>
__global__ __launch_bounds__(256) void treelstm_p2(
    const float* __restrict__ tv,
    const float* __restrict__ wf, const float* __restrict__ uf, const float* __restrict__ bf,
    const float* __restrict__ wi, const float* __restrict__ ui, const float* __restrict__ bi,
    const float* __restrict__ wc, const float* __restrict__ uc, const float* __restrict__ bc,
    const float* __restrict__ wo, const float* __restrict__ uo, const float* __restrict__ bo,
    const float* __restrict__ ws, float* __restrict__ out) {
  const int d = blockIdx.x * 256 + threadIdx.x;

  const Params p = load_params(d, wf, uf, bf, wi, ui, bi, wc, uc, bc, wo, uo, bo);

  float ct;
  float h = top_h<SPLIT, 0>(tv, ws, 0, d, p, ct);
  out[d] = h;
  out[DIM + d] = ct;
}

extern "C" void kernel_launch(void* const* d_in, const int* in_sizes, int n_in,
                              void* d_out, int out_size, void* d_ws, size_t ws_size,
                              hipStream_t stream) {
  const float* tv = (const float*)d_in[0];
  // d_in[1] = depth (int, 13) -- structure hard-coded to depth 13.
  const float* wf = (const float*)d_in[2];
  const float* uf = (const float*)d_in[3];
  const float* bf = (const float*)d_in[4];
  const float* wi = (const float*)d_in[5];
  const float* ui = (const float*)d_in[6];
  const float* bi = (const float*)d_in[7];
  const float* wc = (const float*)d_in[8];
  const float* uc = (const float*)d_in[9];
  const float* bc = (const float*)d_in[10];
  const float* wo = (const float*)d_in[11];
  const float* uo = (const float*)d_in[12];
  const float* bo = (const float*)d_in[13];

  float* ws = (float*)d_ws;
  float* out = (float*)d_out;   // 8192 floats: h then c

  // Split at level 7 (128 subtrees -> 8192 waves = 100% wave capacity) if the
  // 2 MiB of scratch fits; otherwise the level-6 split (1 MiB).
  const size_t need7 = (size_t)128 * DIM * sizeof(float);
  if (ws_size >= need7) {
    treelstm_p1<7><<<dim3(128 * 16), dim3(256), 0, stream>>>(
        tv, wf, uf, bf, wi, ui, bi, wc, uc, bc, wo, uo, bo, ws);
    treelstm_p2<7><<<dim3(16), dim3(256), 0, stream>>>(
        tv, wf, uf, bf, wi, ui, bi, wc, uc, bc, wo, uo, bo, ws, out);
  } else {
    treelstm_p1<6><<<dim3(64 * 16), dim3(256), 0, stream>>>(
        tv, wf, uf, bf, wi, ui, bi, wc, uc, bc, wo, uo, bo, ws);
    treelstm_p2<6><<<dim3(16), dim3(256), 0, stream>>>(
        tv, wf, uf, bf, wi, ui, bi, wc, uc, bc, wo, uo, bo, ws, out);
  }
}